// Round 7
// baseline (464.146 us; speedup 1.0000x reference)
//
#include <hip/hip_runtime.h>

#define DIM 64
#define MTILE 128        // rows per block
#define KCHUNK 128       // codes per staged chunk
#define NCHUNKS 8        // 1024 / 128
#define THREADS 256
#define T_LEN 2048
#define XPITCH 72        // bf16 elems per row (64 + 8 pad)
#define WPITCH 68        // fp32 staging window pitch (overlaid on dmat)
#define PD 132           // dmat pitch (floats): 132%32=4 -> column sweep conflict-free
#define THR 2e-3f        // capture margin (proven bound 1.5e-3)
#define NCAP 8           // per-half-thread top-8 capture

typedef __attribute__((ext_vector_type(8))) short short8;
typedef __attribute__((ext_vector_type(4))) float f32x4;

// monotone order-preserving map float -> u32
__device__ __forceinline__ unsigned int fmap32(float s) {
    unsigned int b = __float_as_uint(s);
    return (b & 0x80000000u) ? ~b : (b | 0x80000000u);
}
__device__ __forceinline__ float funmap32(unsigned int m) {
    unsigned int b = (m & 0x80000000u) ? (m & 0x7fffffffu) : ~m;
    return __uint_as_float(b);
}
// fp32 -> bf16 RTNE
__device__ __forceinline__ unsigned int f2bf(float f) {
    unsigned int u = __float_as_uint(f);
    return (u + 0x7FFFu + ((u >> 16) & 1u)) >> 16;
}
// numpy pairwise-sum (n=64 scalar blocked path) combine tree over 8 partials
__device__ __forceinline__ float np_combine8(const float* r) {
    return __fadd_rn(__fadd_rn(__fadd_rn(r[0], r[1]), __fadd_rn(r[2], r[3])),
                     __fadd_rn(__fadd_rn(r[4], r[5]), __fadd_rn(r[6], r[7])));
}
// numpy-bit-exact distance for one (row, code) pair (verified r2/r3)
__device__ __forceinline__ unsigned long long np_key(
        const float* __restrict__ xr, const float* __restrict__ cr,
        float an, float bn, int k) {
    float acc = 0.0f;
    #pragma unroll
    for (int i = 0; i < DIM; ++i) acc = __fmaf_rn(xr[i], cr[i], acc);
    float t1 = __fadd_rn(an, bn);
    float d  = __fsub_rn(t1, __fmul_rn(2.0f, acc));
    return ((unsigned long long)fmap32(d) << 12) | (unsigned long long)k;
}

__global__ void vq_init_ws(double* ws) { ws[0] = 0.0; }

__global__ void vq_finalize_atomic(const double* __restrict__ ws,
                                   float* __restrict__ out_loss, int n_el) {
    out_loss[0] = (float)(1.25 * ws[0] / (double)n_el);
}

__global__ void vq_finalize_part(const double* __restrict__ ws,
                                 float* __restrict__ out_loss, int n_el) {
    __shared__ double red[8];
    double v = ws[threadIdx.x];
    #pragma unroll
    for (int off = 32; off > 0; off >>= 1) v += __shfl_down(v, off, 64);
    if ((threadIdx.x & 63) == 0) red[threadIdx.x >> 6] = v;
    __syncthreads();
    if (threadIdx.x == 0) {
        double s = 0.0;
        #pragma unroll
        for (int i = 0; i < 8; ++i) s += red[i];
        out_loss[0] = (float)(1.25 * s / (double)n_el);
    }
}

// MFMA bf16 scan materialized to an LDS d-matrix; VALU top-8 sweep with
// trivially-correct id attribution; numpy-bit-exact refine; exhaustive
// np fallback for (provably-detected) capture overflow.
__global__ __launch_bounds__(THREADS) void vq_main(
        const float* __restrict__ x,
        const float* __restrict__ cb,
        float* __restrict__ out_q,
        float* __restrict__ out_idx,
        double* __restrict__ wsd,
        int use_partials)
{
    __shared__ alignas(16) unsigned short xs[MTILE * XPITCH];   // 18432 B
    __shared__ alignas(16) unsigned short cs[KCHUNK * XPITCH];  // 18432 B
    __shared__ alignas(16) float dmat[64 * PD];                 // 33792 B (also fp32 window)
    __shared__ float  bnorm[1024];
    __shared__ float  anorm[MTILE];
    __shared__ int    kstar[MTILE];
    __shared__ double lossd[MTILE];

    const int tid  = threadIdx.x;
    const int lane = tid & 63;
    const int wv   = tid >> 6;         // wave 0..3
    const int col  = lane & 15;
    const int quad = lane >> 4;        // 0..3
    const int r0   = blockIdx.x * MTILE;

    // ---- B_k for all 1024 codes (numpy register routine, verified r2-r4) ----
    #pragma unroll
    for (int j = 0; j < 4; ++j) {
        int k = tid * 4 + j;
        const float4* c4 = (const float4*)(cb + (size_t)k * DIM);
        float r8[8];
        {
            float4 a = c4[0], b = c4[1];
            r8[0] = __fmul_rn(a.x, a.x); r8[1] = __fmul_rn(a.y, a.y);
            r8[2] = __fmul_rn(a.z, a.z); r8[3] = __fmul_rn(a.w, a.w);
            r8[4] = __fmul_rn(b.x, b.x); r8[5] = __fmul_rn(b.y, b.y);
            r8[6] = __fmul_rn(b.z, b.z); r8[7] = __fmul_rn(b.w, b.w);
        }
        #pragma unroll
        for (int m = 1; m < 8; ++m) {
            float4 a = c4[2 * m], b = c4[2 * m + 1];
            r8[0] = __fadd_rn(r8[0], __fmul_rn(a.x, a.x));
            r8[1] = __fadd_rn(r8[1], __fmul_rn(a.y, a.y));
            r8[2] = __fadd_rn(r8[2], __fmul_rn(a.z, a.z));
            r8[3] = __fadd_rn(r8[3], __fmul_rn(a.w, a.w));
            r8[4] = __fadd_rn(r8[4], __fmul_rn(b.x, b.x));
            r8[5] = __fadd_rn(r8[5], __fmul_rn(b.y, b.y));
            r8[6] = __fadd_rn(r8[6], __fmul_rn(b.z, b.z));
            r8[7] = __fadd_rn(r8[7], __fmul_rn(b.w, b.w));
        }
        bnorm[k] = np_combine8(r8);
    }

    // ---- stage x: 2 sub-batches of 64 rows; fp32 window (in dmat) + bf16 xs ----
    float* CSW = dmat;
    const float4* x4 = (const float4*)x;
    for (int sb = 0; sb < 2; ++sb) {
        #pragma unroll
        for (int it = 0; it < 4; ++it) {
            int idx = it * THREADS + tid;
            int row = idx >> 4, f4 = idx & 15;
            float4 v = x4[(size_t)(r0 + sb * 64 + row) * 16 + f4];
            *(float4*)&CSW[row * WPITCH + f4 * 4] = v;
            uint2 pk;
            pk.x = f2bf(v.x) | (f2bf(v.y) << 16);
            pk.y = f2bf(v.z) | (f2bf(v.w) << 16);
            *(uint2*)&xs[(sb * 64 + row) * XPITCH + f4 * 4] = pk;
        }
        __syncthreads();
        // A_n (numpy shuffle routine, verified r2-r4)
        for (int j = 0; j < 16; ++j) {
            int rl = wv * 16 + j;
            float v  = CSW[rl * WPITCH + lane];
            float pp = __fmul_rn(v, v);
            float r = __fadd_rn(pp, __shfl_down(pp, 8, 64));
            r = __fadd_rn(r, __shfl_down(pp, 16, 64));
            r = __fadd_rn(r, __shfl_down(pp, 24, 64));
            r = __fadd_rn(r, __shfl_down(pp, 32, 64));
            r = __fadd_rn(r, __shfl_down(pp, 40, 64));
            r = __fadd_rn(r, __shfl_down(pp, 48, 64));
            r = __fadd_rn(r, __shfl_down(pp, 56, 64));
            float rr[8];
            #pragma unroll
            for (int q = 0; q < 8; ++q) rr[q] = __shfl(r, q, 64);
            if (lane == 0) anorm[sb * 64 + rl] = np_combine8(rr);
        }
        __syncthreads();
    }

    // ---- A fragments: all 8 m-tiles per wave, loaded once ----
    short8 afr[8][2];
    #pragma unroll
    for (int mt = 0; mt < 8; ++mt)
        #pragma unroll
        for (int kh = 0; kh < 2; ++kh)
            afr[mt][kh] = *(const short8*)&xs[(mt * 16 + col) * XPITCH + kh * 32 + quad * 8];

    // ---- per-thread top-8 over (row = tid>>1, half = tid&1) code slices ----
    const int myrow  = tid >> 1;
    const int myhalf = tid & 1;
    float d8[NCAP];
    int   id8[NCAP];
    #pragma unroll
    for (int s = 0; s < NCAP; ++s) { d8[s] = 3.4e38f; id8[s] = 0; }

    for (int ch = 0; ch < NCHUNKS; ++ch) {
        __syncthreads();   // dmat/cs free (prior sweep done; ch0: staging done)
        #pragma unroll
        for (int it = 0; it < 8; ++it) {
            int idx = it * THREADS + tid;
            int row = idx >> 4, f4 = idx & 15;
            float4 v = ((const float4*)cb)[(size_t)(ch * KCHUNK + row) * 16 + f4];
            uint2 pk;
            pk.x = f2bf(v.x) | (f2bf(v.y) << 16);
            pk.y = f2bf(v.z) | (f2bf(v.w) << 16);
            *(uint2*)&cs[row * XPITCH + f4 * 4] = pk;
        }
        __syncthreads();   // cs staged

        #pragma unroll
        for (int sub = 0; sub < 2; ++sub) {
            // wave wv owns code tile nt = sub*4+wv -> dmat rows wv*16+col
            const int nt = sub * 4 + wv;
            short8 b0 = *(const short8*)&cs[(nt * 16 + col) * XPITCH + quad * 8];
            short8 b1 = *(const short8*)&cs[(nt * 16 + col) * XPITCH + 32 + quad * 8];
            const float bn = bnorm[ch * KCHUNK + nt * 16 + col];
            #pragma unroll
            for (int mt = 0; mt < 8; ++mt) {
                f32x4 acc = {0.f, 0.f, 0.f, 0.f};
                acc = __builtin_amdgcn_mfma_f32_16x16x32_bf16(afr[mt][0], b0, acc, 0, 0, 0);
                acc = __builtin_amdgcn_mfma_f32_16x16x32_bf16(afr[mt][1], b1, acc, 0, 0, 0);
                float4 dv;   // d~ for rows mt*16+quad*4+{0..3}, code nt*16+col
                dv.x = fmaf(-2.0f, acc[0], bn);
                dv.y = fmaf(-2.0f, acc[1], bn);
                dv.z = fmaf(-2.0f, acc[2], bn);
                dv.w = fmaf(-2.0f, acc[3], bn);
                *(float4*)&dmat[(wv * 16 + col) * PD + mt * 16 + quad * 4] = dv;
            }
            __syncthreads();   // dmat ready

            // VALU sweep: value+id read together -> attribution trivially correct
            const int cbase = ch * KCHUNK + sub * 64;
            for (int j = 0; j < 32; ++j) {
                int c = myhalf * 32 + j;
                float d = dmat[c * PD + myrow];
                if (d < d8[NCAP - 1]) {
                    d8[NCAP - 1] = d; id8[NCAP - 1] = cbase + c;
                    #pragma unroll
                    for (int s = NCAP - 1; s > 0; --s) {
                        if (d8[s] < d8[s - 1]) {
                            float td = d8[s - 1]; d8[s - 1] = d8[s]; d8[s] = td;
                            int ti = id8[s - 1]; id8[s - 1] = id8[s]; id8[s] = ti;
                        }
                    }
                }
            }
            __syncthreads();   // sweep done before dmat overwrite
        }
    }

    // ---- per-row combine (threads 2r, 2r+1 are lane-adjacent in one wave) ----
    float rmin = fminf(d8[0], __shfl_xor(d8[0], 1, 64));
    const float lim = rmin + THR;
    int ovf = (d8[NCAP - 1] <= lim) ? 1 : 0;
    ovf |= __shfl_xor(ovf, 1, 64);

    const float* xr = x + (size_t)(r0 + myrow) * DIM;
    const float  an = anorm[myrow];
    unsigned long long best = ~0ULL;
    if (!ovf) {
        #pragma unroll
        for (int s = 0; s < NCAP; ++s) {
            if (d8[s] <= lim) {
                int k = id8[s];
                unsigned long long key = np_key(xr, cb + (size_t)k * DIM, an, bnorm[k], k);
                best = (key < best) ? key : best;
            }
        }
    } else {
        // exhaustive np-exact fallback, pair-split (expected ~never)
        for (int i = 0; i < 512; ++i) {
            int k = myhalf * 512 + i;
            unsigned long long key = np_key(xr, cb + (size_t)k * DIM, an, bnorm[k], k);
            best = (key < best) ? key : best;
        }
    }
    unsigned long long ob = __shfl_xor(best, 1, 64);
    best = (ob < best) ? ob : best;
    if (myhalf == 0) {
        kstar[myrow] = (int)(best & 0xFFFULL);
        lossd[myrow] = (double)funmap32((unsigned int)(best >> 12));
    }
    __syncthreads();

    // ---- epilogue: indices (as float), transposed quantized, loss ----
    if (tid < MTILE) out_idx[r0 + tid] = (float)kstar[tid];

    const int bb = r0 / T_LEN;
    const int t0 = r0 % T_LEN;
    const int t  = tid & 127, half = tid >> 7;
    const int kt = kstar[t];
    #pragma unroll
    for (int it = 0; it < 32; ++it) {
        int d = it * 2 + half;
        out_q[((size_t)bb * DIM + d) * T_LEN + (t0 + t)] = cb[(size_t)kt * DIM + d];
    }

    if (tid < 64) {
        double v = lossd[tid] + lossd[tid + 64];
        #pragma unroll
        for (int off = 32; off > 0; off >>= 1) v += __shfl_down(v, off, 64);
        if (tid == 0) {
            if (use_partials) wsd[blockIdx.x] = v;
            else atomicAdd(wsd, v);
        }
    }
}

extern "C" void kernel_launch(void* const* d_in, const int* in_sizes, int n_in,
                              void* d_out, int out_size, void* d_ws, size_t ws_size,
                              hipStream_t stream) {
    const float* x  = (const float*)d_in[0];
    const float* cb = (const float*)d_in[1];
    float* out = (float*)d_out;

    const int n_x = in_sizes[0];           // 4194304
    const int n_rows = n_x / DIM;          // 65536
    const int n_blocks = n_rows / MTILE;   // 512

    float* out_q    = out;                    // [B, D, T]
    float* out_loss = out + (size_t)n_x;      // scalar
    float* out_idx  = out + (size_t)n_x + 1;  // [B, T] as float
    double* wsd = (double*)d_ws;

    const int use_partials = (ws_size >= (size_t)n_blocks * sizeof(double)) ? 1 : 0;
    if (!use_partials) vq_init_ws<<<1, 1, 0, stream>>>(wsd);
    vq_main<<<n_blocks, THREADS, 0, stream>>>(x, cb, out_q, out_idx, wsd, use_partials);
    if (use_partials) vq_finalize_part<<<1, 512, 0, stream>>>(wsd, out_loss, n_x);
    else vq_finalize_atomic<<<1, 1, 0, stream>>>(wsd, out_loss, n_x);
}

// Round 8
// 192.064 us; speedup vs baseline: 2.4166x; 2.4166x over previous
//
#include <hip/hip_runtime.h>

#define DIM 64
#define MTILE 128        // rows per block
#define NCHUNKS 8        // 1024 / 128 codes per chunk
#define THREADS 256
#define T_LEN 2048
#define WPITCH 68        // fp32 anorm staging window pitch (overlaid on dmat)
#define PD 132           // dmat pitch (floats): column sweep conflict-free (proven r6)
#define THR 2e-3f        // capture margin (proven pairwise bound 1.53e-3)
#define CAP 10           // per-thread candidate list capacity

typedef __attribute__((ext_vector_type(8))) short short8;
typedef __attribute__((ext_vector_type(4))) float f32x4;

// monotone order-preserving map float -> u32
__device__ __forceinline__ unsigned int fmap32(float s) {
    unsigned int b = __float_as_uint(s);
    return (b & 0x80000000u) ? ~b : (b | 0x80000000u);
}
__device__ __forceinline__ float funmap32(unsigned int m) {
    unsigned int b = (m & 0x80000000u) ? (m & 0x7fffffffu) : ~m;
    return __uint_as_float(b);
}
// fp32 -> bf16 RTNE
__device__ __forceinline__ unsigned int f2bf(float f) {
    unsigned int u = __float_as_uint(f);
    return (u + 0x7FFFu + ((u >> 16) & 1u)) >> 16;
}
// numpy pairwise-sum (n=64 scalar blocked path) combine tree over 8 partials
__device__ __forceinline__ float np_combine8(const float* r) {
    return __fadd_rn(__fadd_rn(__fadd_rn(r[0], r[1]), __fadd_rn(r[2], r[3])),
                     __fadd_rn(__fadd_rn(r[4], r[5]), __fadd_rn(r[6], r[7])));
}
// numpy-bit-exact distance key for one (row, code) pair (verified r2-r6)
__device__ __forceinline__ unsigned long long np_key(
        const float* __restrict__ xr, const float* __restrict__ cr,
        float an, float bn, int k) {
    float acc = 0.0f;
    #pragma unroll
    for (int i = 0; i < DIM; ++i) acc = __fmaf_rn(xr[i], cr[i], acc);
    float t1 = __fadd_rn(an, bn);
    float d  = __fsub_rn(t1, __fmul_rn(2.0f, acc));
    return ((unsigned long long)fmap32(d) << 12) | (unsigned long long)k;
}

__global__ void vq_init_ws(double* ws) { ws[0] = 0.0; }

__global__ void vq_finalize_atomic(const double* __restrict__ ws,
                                   float* __restrict__ out_loss, int n_el) {
    out_loss[0] = (float)(1.25 * ws[0] / (double)n_el);
}

__global__ void vq_finalize_part(const double* __restrict__ ws,
                                 float* __restrict__ out_loss, int n_el) {
    __shared__ double red[8];
    double v = ws[threadIdx.x];
    #pragma unroll
    for (int off = 32; off > 0; off >>= 1) v += __shfl_down(v, off, 64);
    if ((threadIdx.x & 63) == 0) red[threadIdx.x >> 6] = v;
    __syncthreads();
    if (threadIdx.x == 0) {
        double s = 0.0;
        #pragma unroll
        for (int i = 0; i < 8; ++i) s += red[i];
        out_loss[0] = (float)(1.25 * s / (double)n_el);
    }
}

// MFMA bf16 scan -> LDS d-matrix -> branchless tree-min sweep with running-lim
// candidate capture (single-writer lists, superset-safe) -> np-bit-exact refine.
// Overflowed rows (P ~ 1e-5) fall back to a wave-parallel exhaustive np scan.
__global__ __launch_bounds__(THREADS) void vq_main(
        const float* __restrict__ x,
        const float* __restrict__ cb,
        float* __restrict__ out_q,
        float* __restrict__ out_idx,
        double* __restrict__ wsd,
        int use_partials)
{
    __shared__ alignas(16) float dmat[64 * PD];   // 33792 B (also fp32 anorm window)
    __shared__ float  bnorm[1024];
    __shared__ float  anorm[MTILE];
    __shared__ int    kstar[MTILE];
    __shared__ double lossd[MTILE];
    __shared__ unsigned short clist[THREADS * CAP];
    __shared__ int    ovfrows[MTILE];
    __shared__ int    ovfcnt;

    const int tid  = threadIdx.x;
    const int lane = tid & 63;
    const int wv   = tid >> 6;         // wave 0..3
    const int col  = lane & 15;
    const int quad = lane >> 4;        // 0..3
    const int r0   = blockIdx.x * MTILE;

    if (tid == 0) ovfcnt = 0;

    // ---- B_k for all 1024 codes (numpy register routine, verified r2-r6) ----
    #pragma unroll
    for (int j = 0; j < 4; ++j) {
        int k = tid * 4 + j;
        const float4* c4 = (const float4*)(cb + (size_t)k * DIM);
        float r8[8];
        {
            float4 a = c4[0], b = c4[1];
            r8[0] = __fmul_rn(a.x, a.x); r8[1] = __fmul_rn(a.y, a.y);
            r8[2] = __fmul_rn(a.z, a.z); r8[3] = __fmul_rn(a.w, a.w);
            r8[4] = __fmul_rn(b.x, b.x); r8[5] = __fmul_rn(b.y, b.y);
            r8[6] = __fmul_rn(b.z, b.z); r8[7] = __fmul_rn(b.w, b.w);
        }
        #pragma unroll
        for (int m = 1; m < 8; ++m) {
            float4 a = c4[2 * m], b = c4[2 * m + 1];
            r8[0] = __fadd_rn(r8[0], __fmul_rn(a.x, a.x));
            r8[1] = __fadd_rn(r8[1], __fmul_rn(a.y, a.y));
            r8[2] = __fadd_rn(r8[2], __fmul_rn(a.z, a.z));
            r8[3] = __fadd_rn(r8[3], __fmul_rn(a.w, a.w));
            r8[4] = __fadd_rn(r8[4], __fmul_rn(b.x, b.x));
            r8[5] = __fadd_rn(r8[5], __fmul_rn(b.y, b.y));
            r8[6] = __fadd_rn(r8[6], __fmul_rn(b.z, b.z));
            r8[7] = __fadd_rn(r8[7], __fmul_rn(b.w, b.w));
        }
        bnorm[k] = np_combine8(r8);
    }

    // ---- A_n for 128 rows via fp32 window overlaid on dmat (verified r2-r6) ----
    float* CSW = dmat;
    const float4* x4 = (const float4*)x;
    for (int sb = 0; sb < 2; ++sb) {
        #pragma unroll
        for (int it = 0; it < 4; ++it) {
            int idx = it * THREADS + tid;
            int row = idx >> 4, f4 = idx & 15;
            float4 v = x4[(size_t)(r0 + sb * 64 + row) * 16 + f4];
            *(float4*)&CSW[row * WPITCH + f4 * 4] = v;
        }
        __syncthreads();
        for (int j = 0; j < 16; ++j) {
            int rl = wv * 16 + j;
            float v  = CSW[rl * WPITCH + lane];
            float pp = __fmul_rn(v, v);
            float r = __fadd_rn(pp, __shfl_down(pp, 8, 64));
            r = __fadd_rn(r, __shfl_down(pp, 16, 64));
            r = __fadd_rn(r, __shfl_down(pp, 24, 64));
            r = __fadd_rn(r, __shfl_down(pp, 32, 64));
            r = __fadd_rn(r, __shfl_down(pp, 40, 64));
            r = __fadd_rn(r, __shfl_down(pp, 48, 64));
            r = __fadd_rn(r, __shfl_down(pp, 56, 64));
            float rr[8];
            #pragma unroll
            for (int q = 0; q < 8; ++q) rr[q] = __shfl(r, q, 64);
            if (lane == 0) anorm[sb * 64 + rl] = np_combine8(rr);
        }
        __syncthreads();
    }

    // ---- A fragments direct from global with in-lane bf16 convert ----
    short8 afr[8][2];
    #pragma unroll
    for (int mt = 0; mt < 8; ++mt) {
        #pragma unroll
        for (int kh = 0; kh < 2; ++kh) {
            const float* ap = x + (size_t)(r0 + mt * 16 + col) * DIM + kh * 32 + quad * 8;
            float4 a = *(const float4*)ap;
            float4 b = *(const float4*)(ap + 4);
            short8 s;
            s[0] = (short)f2bf(a.x); s[1] = (short)f2bf(a.y);
            s[2] = (short)f2bf(a.z); s[3] = (short)f2bf(a.w);
            s[4] = (short)f2bf(b.x); s[5] = (short)f2bf(b.y);
            s[6] = (short)f2bf(b.z); s[7] = (short)f2bf(b.w);
            afr[mt][kh] = s;
        }
    }

    const int myrow  = tid >> 1;
    const int myhalf = tid & 1;
    float runmin = 3.4e38f;
    int cnt = 0;

    // ---- main loop: 8 chunks x 2 subs of 64 codes ----
    for (int ch = 0; ch < NCHUNKS; ++ch) {
        #pragma unroll
        for (int sub = 0; sub < 2; ++sub) {
            const int kc = ch * 128;
            const int nt = sub * 4 + wv;          // this wave's 16-code tile
            // B fragments direct from global (L2-hot), in-lane convert
            const float* bp = cb + (size_t)(kc + nt * 16 + col) * DIM + quad * 8;
            float4 a0 = *(const float4*)bp;
            float4 a1 = *(const float4*)(bp + 4);
            float4 c0 = *(const float4*)(bp + 32);
            float4 c1 = *(const float4*)(bp + 36);
            short8 b0, b1;
            b0[0] = (short)f2bf(a0.x); b0[1] = (short)f2bf(a0.y);
            b0[2] = (short)f2bf(a0.z); b0[3] = (short)f2bf(a0.w);
            b0[4] = (short)f2bf(a1.x); b0[5] = (short)f2bf(a1.y);
            b0[6] = (short)f2bf(a1.z); b0[7] = (short)f2bf(a1.w);
            b1[0] = (short)f2bf(c0.x); b1[1] = (short)f2bf(c0.y);
            b1[2] = (short)f2bf(c0.z); b1[3] = (short)f2bf(c0.w);
            b1[4] = (short)f2bf(c1.x); b1[5] = (short)f2bf(c1.y);
            b1[6] = (short)f2bf(c1.z); b1[7] = (short)f2bf(c1.w);
            const float bn = bnorm[kc + nt * 16 + col];

            __syncthreads();   // (A) prior sweep done / anorm window dead
            #pragma unroll
            for (int mt = 0; mt < 8; ++mt) {
                f32x4 acc = {0.f, 0.f, 0.f, 0.f};
                acc = __builtin_amdgcn_mfma_f32_16x16x32_bf16(afr[mt][0], b0, acc, 0, 0, 0);
                acc = __builtin_amdgcn_mfma_f32_16x16x32_bf16(afr[mt][1], b1, acc, 0, 0, 0);
                float4 dv;   // d~ for rows mt*16+quad*4+{0..3}, dmat code wv*16+col
                dv.x = fmaf(-2.0f, acc[0], bn);
                dv.y = fmaf(-2.0f, acc[1], bn);
                dv.z = fmaf(-2.0f, acc[2], bn);
                dv.w = fmaf(-2.0f, acc[3], bn);
                *(float4*)&dmat[(wv * 16 + col) * PD + mt * 16 + quad * 4] = dv;
            }
            __syncthreads();   // (B) dmat ready

            // branchless tree-min sweep; reads proven conflict-free (r6)
            float v[32];
            #pragma unroll
            for (int j = 0; j < 32; ++j)
                v[j] = dmat[(myhalf * 32 + j) * PD + myrow];
            float m16[16];
            #pragma unroll
            for (int j = 0; j < 16; ++j) m16[j] = fminf(v[j], v[j + 16]);
            float m8[8];
            #pragma unroll
            for (int j = 0; j < 8; ++j) m8[j] = fminf(m16[j], m16[j + 8]);
            float m4[4];
            #pragma unroll
            for (int j = 0; j < 4; ++j) m4[j] = fminf(m8[j], m8[j + 4]);
            float mloc = fminf(fminf(m4[0], m4[1]), fminf(m4[2], m4[3]));
            float mp = fminf(mloc, __shfl_xor(mloc, 1, 64));   // pair merge
            runmin = fminf(runmin, mp);
            const float lim = runmin + THR;
            const int cbase = ch * 128 + sub * 64 + myhalf * 32;
            #pragma unroll
            for (int j = 0; j < 32; ++j) {
                if (v[j] <= lim) {
                    if (cnt < CAP)
                        clist[tid * CAP + cnt] = (unsigned short)(cbase + j);
                    ++cnt;
                }
            }
        }
    }

    // ---- np-bit-exact refine of own candidate list; pair merge ----
    const float* xr = x + (size_t)(r0 + myrow) * DIM;
    const float  an = anorm[myrow];
    unsigned long long best = ~0ULL;
    {
        int n = (cnt > CAP) ? CAP : cnt;
        for (int j = 0; j < n; ++j) {
            int k = clist[tid * CAP + j];
            unsigned long long key = np_key(xr, cb + (size_t)k * DIM, an, bnorm[k], k);
            best = (key < best) ? key : best;
        }
    }
    unsigned long long ob = __shfl_xor(best, 1, 64);
    best = (ob < best) ? ob : best;
    int ovf = (cnt > CAP) ? 1 : 0;
    ovf |= __shfl_xor(ovf, 1, 64);
    if (myhalf == 0) {
        if (ovf) {
            int s = atomicAdd(&ovfcnt, 1);
            ovfrows[s] = myrow;
        } else {
            kstar[myrow] = (int)(best & 0xFFFULL);
            lossd[myrow] = (double)funmap32((unsigned int)(best >> 12));
        }
    }
    __syncthreads();

    // ---- wave-parallel exhaustive np fallback for overflowed rows (rare) ----
    const int ovfn = ovfcnt;
    for (int i = wv; i < ovfn; i += 4) {
        const int row = ovfrows[i];
        const float* xr2 = x + (size_t)(r0 + row) * DIM;
        const float an2 = anorm[row];
        unsigned long long b2 = ~0ULL;
        for (int j = 0; j < 16; ++j) {
            int k = lane * 16 + j;
            unsigned long long key = np_key(xr2, cb + (size_t)k * DIM, an2, bnorm[k], k);
            b2 = (key < b2) ? key : b2;
        }
        #pragma unroll
        for (int off = 1; off < 64; off <<= 1) {
            unsigned long long o = __shfl_xor(b2, off, 64);
            b2 = (o < b2) ? o : b2;
        }
        if (lane == 0) {
            kstar[row] = (int)(b2 & 0xFFFULL);
            lossd[row] = (double)funmap32((unsigned int)(b2 >> 12));
        }
    }
    __syncthreads();

    // ---- epilogue: indices (as float), transposed quantized, loss (verified) ----
    if (tid < MTILE) out_idx[r0 + tid] = (float)kstar[tid];

    const int bb = r0 / T_LEN;
    const int t0 = r0 % T_LEN;
    const int t  = tid & 127, half = tid >> 7;
    const int kt = kstar[t];
    #pragma unroll
    for (int it = 0; it < 32; ++it) {
        int d = it * 2 + half;
        out_q[((size_t)bb * DIM + d) * T_LEN + (t0 + t)] = cb[(size_t)kt * DIM + d];
    }

    if (tid < 64) {
        double v = lossd[tid] + lossd[tid + 64];
        #pragma unroll
        for (int off = 32; off > 0; off >>= 1) v += __shfl_down(v, off, 64);
        if (tid == 0) {
            if (use_partials) wsd[blockIdx.x] = v;
            else atomicAdd(wsd, v);
        }
    }
}

extern "C" void kernel_launch(void* const* d_in, const int* in_sizes, int n_in,
                              void* d_out, int out_size, void* d_ws, size_t ws_size,
                              hipStream_t stream) {
    const float* x  = (const float*)d_in[0];
    const float* cb = (const float*)d_in[1];
    float* out = (float*)d_out;

    const int n_x = in_sizes[0];           // 4194304
    const int n_rows = n_x / DIM;          // 65536
    const int n_blocks = n_rows / MTILE;   // 512

    float* out_q    = out;                    // [B, D, T]
    float* out_loss = out + (size_t)n_x;      // scalar
    float* out_idx  = out + (size_t)n_x + 1;  // [B, T] as float
    double* wsd = (double*)d_ws;

    const int use_partials = (ws_size >= (size_t)n_blocks * sizeof(double)) ? 1 : 0;
    if (!use_partials) vq_init_ws<<<1, 1, 0, stream>>>(wsd);
    vq_main<<<n_blocks, THREADS, 0, stream>>>(x, cb, out_q, out_idx, wsd, use_partials);
    if (use_partials) vq_finalize_part<<<1, 512, 0, stream>>>(wsd, out_loss, n_x);
    else vq_finalize_atomic<<<1, 1, 0, stream>>>(wsd, out_loss, n_x);
}